// Round 2
// baseline (515.150 us; speedup 1.0000x reference)
//
#include <hip/hip_runtime.h>
#include <hip/hip_bf16.h>

using bf16 = __hip_bfloat16;
using s8v  = __attribute__((ext_vector_type(8))) short;
using f4v  = __attribute__((ext_vector_type(4))) float;

constexpr int B_   = 4;
constexpr int P_   = 1024;
constexpr int KNB  = 32;
constexpr int D_   = 768;
constexpr int H_   = 12;
constexpr int S_   = P_ + 1;    // 1025
constexpr int M_   = B_ * S_;   // 4100
constexpr int MPAD = 4224;      // 33 * 128

#define DEVI static __device__ __forceinline__

DEVI float b2f_lo(unsigned u) { return __builtin_bit_cast(float, u << 16); }
DEVI float b2f_hi(unsigned u) { return __builtin_bit_cast(float, u & 0xffff0000u); }

// ---------------- weight fp32 (K x N) -> bf16 transposed (N x K) ----------------
template<int KK, int NN>
__global__ __launch_bounds__(256)
void wt_conv(const float* __restrict__ W, bf16* __restrict__ Wt) {
  __shared__ float t[32][33];
  int bk = blockIdx.x * 32, bn = blockIdx.y * 32;
  int tx = threadIdx.x & 31, ty = threadIdx.x >> 5;  // ty in 0..7
#pragma unroll
  for (int i = 0; i < 32; i += 8)
    t[ty + i][tx] = W[(size_t)(bk + ty + i) * NN + bn + tx];
  __syncthreads();
#pragma unroll
  for (int i = 0; i < 32; i += 8)
    Wt[(size_t)(bn + ty + i) * KK + bk + tx] = __float2bfloat16(t[tx][ty + i]);
}

// ---------------- LayerNorm fp32 -> bf16 (row = 768) ----------------
__global__ __launch_bounds__(256)
void ln_kernel(const float* __restrict__ x, const float* __restrict__ w,
               const float* __restrict__ b, bf16* __restrict__ out) {
  int row = blockIdx.x;
  const float* xr = x + (size_t)row * D_;
  int t = threadIdx.x;
  float v0 = xr[t], v1 = xr[t + 256], v2 = xr[t + 512];
  float s = v0 + v1 + v2;
  float ss = v0 * v0 + v1 * v1 + v2 * v2;
#pragma unroll
  for (int o = 32; o; o >>= 1) { s += __shfl_xor(s, o); ss += __shfl_xor(ss, o); }
  __shared__ float sm[4], sv[4];
  if ((t & 63) == 0) { sm[t >> 6] = s; sv[t >> 6] = ss; }
  __syncthreads();
  float S = sm[0] + sm[1] + sm[2] + sm[3];
  float SS = sv[0] + sv[1] + sv[2] + sv[3];
  float mean = S * (1.f / D_);
  float var  = SS * (1.f / D_) - mean * mean;
  float inv  = rsqrtf(var + 1e-5f);
  bf16* orow = out + (size_t)row * D_;
  orow[t]       = __float2bfloat16((v0 - mean) * inv * w[t]       + b[t]);
  orow[t + 256] = __float2bfloat16((v1 - mean) * inv * w[t + 256] + b[t + 256]);
  orow[t + 512] = __float2bfloat16((v2 - mean) * inv * w[t + 512] + b[t + 512]);
}

// ---------------- bf16 GEMM: C = A(MPADxKSTRIDE) * Bt(NxKSTRIDE)^T over K-chunk ----------------
// MODE 0: + bias -> scatter to QKV buffer [3][B][S][768] bf16
// MODE 2: + bias -> gelu(exact) -> bf16 dst [MPAD][N]
// MODE 3: atomicAdd fp32 partial into dst [M][N]   (split-K; bias handled by init kernel)
template<int N, int KSTRIDE, int KCHUNK, int MODE>
__global__ __launch_bounds__(256)
void gemm_bf16(const bf16* __restrict__ A, const bf16* __restrict__ Bt,
               const float* __restrict__ bias, void* __restrict__ dst) {
  __shared__ bf16 lds[2][2][128 * 32];
  const int tm = blockIdx.x, tn = blockIdx.y;
  const int kbase = blockIdx.z * KCHUNK;
  const int tid = threadIdx.x;
  const int wid = tid >> 6, lane = tid & 63;
  const int wr = wid >> 1, wc = wid & 1;

  auto stage = [&](int bufi, int step) {
    const int k0 = kbase + step * 32;
#pragma unroll
    for (int i = 0; i < 2; ++i) {
      int c = wid * 64 + i * 256 + lane;
      int r = c >> 2, slot = c & 3;
      int gs = slot ^ ((r >> 1) & 3);  // inverse-swizzled global source (rule 21)
      const bf16* ga = A + (size_t)(tm * 128 + r) * KSTRIDE + k0 + gs * 8;
      bf16* la = &lds[bufi][0][(wid * 64 + i * 256) * 8];
      __builtin_amdgcn_global_load_lds(
          (__attribute__((address_space(1))) void*)ga,
          (__attribute__((address_space(3))) void*)la, 16, 0, 0);
    }
#pragma unroll
    for (int i = 0; i < 2; ++i) {
      int c = wid * 64 + i * 256 + lane;
      int r = c >> 2, slot = c & 3;
      int gs = slot ^ ((r >> 1) & 3);
      const bf16* ga = Bt + (size_t)(tn * 128 + r) * KSTRIDE + k0 + gs * 8;
      bf16* la = &lds[bufi][1][(wid * 64 + i * 256) * 8];
      __builtin_amdgcn_global_load_lds(
          (__attribute__((address_space(1))) void*)ga,
          (__attribute__((address_space(3))) void*)la, 16, 0, 0);
    }
  };

  f4v acc[4][4] = {};

  stage(0, 0);
  __syncthreads();
  int buf = 0;
  const int nk = KCHUNK / 32;
  for (int kt = 0; kt < nk; ++kt) {
    if (kt + 1 < nk) stage(buf ^ 1, kt + 1);
    s8v af[4], bfv[4];
#pragma unroll
    for (int m = 0; m < 4; ++m) {
      int row = wr * 64 + m * 16 + (lane & 15);
      int slot = (lane >> 4) ^ ((row >> 1) & 3);
      af[m] = *(const s8v*)&lds[buf][0][row * 32 + slot * 8];
    }
#pragma unroll
    for (int n = 0; n < 4; ++n) {
      int row = wc * 64 + n * 16 + (lane & 15);
      int slot = (lane >> 4) ^ ((row >> 1) & 3);
      bfv[n] = *(const s8v*)&lds[buf][1][row * 32 + slot * 8];
    }
#pragma unroll
    for (int m = 0; m < 4; ++m)
#pragma unroll
      for (int n = 0; n < 4; ++n)
        acc[m][n] = __builtin_amdgcn_mfma_f32_16x16x32_bf16(af[m], bfv[n], acc[m][n], 0, 0, 0);
    __syncthreads();
    buf ^= 1;
  }

#pragma unroll
  for (int m = 0; m < 4; ++m)
#pragma unroll
    for (int n = 0; n < 4; ++n)
#pragma unroll
      for (int j = 0; j < 4; ++j) {
        int row = tm * 128 + wr * 64 + m * 16 + (lane >> 4) * 4 + j;  // C: row=(l>>4)*4+j
        int col = tn * 128 + wc * 64 + n * 16 + (lane & 15);          //    col=l&15 (m89)
        float v = acc[m][n][j];
        if (MODE == 0) {
          if (row < M_) {
            float val = v + bias[col];
            int which = col / 768, rem = col % 768;
            int bb = row / S_, s = row % S_;
            ((bf16*)dst)[((size_t)(which * B_ + bb) * S_ + s) * 768 + rem] =
                __float2bfloat16(val);
          }
        } else if (MODE == 2) {
          float val = v + bias[col];
          val = 0.5f * val * (1.f + erff(val * 0.70710678f));
          ((bf16*)dst)[(size_t)row * N + col] = __float2bfloat16(val);
        } else {
          if (row < M_) atomicAdd(&((float*)dst)[(size_t)row * N + col], v);
        }
      }
}

// ---------------- split-K epilogue init kernels ----------------
__global__ __launch_bounds__(256)
void init_out_xb(const float* __restrict__ x, const float* __restrict__ bias,
                 float* __restrict__ out) {
  int i = blockIdx.x * 256 + threadIdx.x;          // float4 index; M_*768/4 total
  float4 xv = ((const float4*)x)[i];
  int col = (i * 4) % D_;
  float4 bv = *(const float4*)&bias[col];
  float4 o = make_float4(xv.x + bv.x, xv.y + bv.y, xv.z + bv.z, xv.w + bv.w);
  ((float4*)out)[i] = o;
}

__global__ __launch_bounds__(256)
void add_bias_ip(float* __restrict__ out, const float* __restrict__ bias) {
  int i = blockIdx.x * 256 + threadIdx.x;
  float4 ov = ((const float4*)out)[i];
  int col = (i * 4) % D_;
  float4 bv = *(const float4*)&bias[col];
  float4 o = make_float4(ov.x + bv.x, ov.y + bv.y, ov.z + bv.z, ov.w + bv.w);
  ((float4*)out)[i] = o;
}

// ---------------- cls-token attention: block per (b,h), softmax over S keys ----------------
__global__ __launch_bounds__(256)
void cls_attn(const bf16* __restrict__ QKV, bf16* __restrict__ out) {
  int b = blockIdx.x / H_, h = blockIdx.x % H_;
  const bf16* q  = QKV + ((size_t)(0 * B_ + b) * S_) * D_ + h * 64;
  const bf16* Kr = QKV + ((size_t)(1 * B_ + b) * S_) * D_ + h * 64;
  const bf16* Vr = QKV + ((size_t)(2 * B_ + b) * S_) * D_ + h * 64;
  __shared__ float qf[64];
  __shared__ float sc[S_];
  __shared__ float redm[4], reds[4];
  __shared__ float pv[4][64];
  int t = threadIdx.x;
  if (t < 64) qf[t] = __bfloat162float(q[t]);
  __syncthreads();
  for (int k = t; k < S_; k += 256) {
    const uint4* k4 = (const uint4*)(Kr + (size_t)k * D_);
    float s = 0.f;
#pragma unroll
    for (int i = 0; i < 8; ++i) {
      uint4 kv = k4[i];
      const float* q8 = &qf[i * 8];
      s += b2f_lo(kv.x) * q8[0] + b2f_hi(kv.x) * q8[1]
         + b2f_lo(kv.y) * q8[2] + b2f_hi(kv.y) * q8[3]
         + b2f_lo(kv.z) * q8[4] + b2f_hi(kv.z) * q8[5]
         + b2f_lo(kv.w) * q8[6] + b2f_hi(kv.w) * q8[7];
    }
    sc[k] = s * 0.125f;
  }
  __syncthreads();
  float mx = -1e30f;
  for (int k = t; k < S_; k += 256) mx = fmaxf(mx, sc[k]);
#pragma unroll
  for (int o = 32; o; o >>= 1) mx = fmaxf(mx, __shfl_xor(mx, o));
  if ((t & 63) == 0) redm[t >> 6] = mx;
  __syncthreads();
  mx = fmaxf(fmaxf(redm[0], redm[1]), fmaxf(redm[2], redm[3]));
  float sum = 0.f;
  for (int k = t; k < S_; k += 256) { float e = __expf(sc[k] - mx); sc[k] = e; sum += e; }
#pragma unroll
  for (int o = 32; o; o >>= 1) sum += __shfl_xor(sum, o);
  if ((t & 63) == 0) reds[t >> 6] = sum;
  __syncthreads();
  sum = reds[0] + reds[1] + reds[2] + reds[3];
  float inv = 1.f / sum;
  int d = t & 63, kg = t >> 6;
  float acc = 0.f;
  for (int k = kg; k < S_; k += 4) acc += sc[k] * __bfloat162float(Vr[(size_t)k * D_ + d]);
  pv[kg][d] = acc;
  __syncthreads();
  if (t < 64) {
    float ov = (pv[0][t] + pv[1][t] + pv[2][t] + pv[3][t]) * inv;
    out[(size_t)(b * S_) * D_ + h * 64 + t] = __float2bfloat16(ov);
  }
}

// ---------------- routed attention: block per (b,p); 12 waves = 12 heads ----------------
__global__ __launch_bounds__(768)
void routed_attn(const bf16* __restrict__ QKV, const int* __restrict__ routes,
                 bf16* __restrict__ out) {
  int idx = blockIdx.x;
  int b = (idx >> 1) & 3;                       // XCD-affinity heuristic: b tied to idx%8
  int p = ((idx >> 3) << 1) | (idx & 1);
  int tid = threadIdx.x;
  int h = tid >> 6, lane = tid & 63;
  __shared__ int ridx[KNB];
  __shared__ float qf[D_];
  __shared__ float sc[H_][KNB];
  if (tid < KNB) ridx[tid] = routes[p * KNB + tid] + 1;
  qf[tid] = __bfloat162float(QKV[((size_t)(0 * B_ + b) * S_ + (p + 1)) * D_ + tid]);
  __syncthreads();
  const bf16* Kb = QKV + ((size_t)(1 * B_ + b) * S_) * D_;
  const bf16* Vb = QKV + ((size_t)(2 * B_ + b) * S_) * D_;
  // phase 1: lane = (key k, half hi); each lane does a 32-dim half-dot
  int k = lane & 31, hi = lane >> 5;
  int sk = ridx[k];
  const uint4* kr = (const uint4*)(Kb + (size_t)sk * D_ + h * 64 + hi * 32);
  const float* qp = &qf[h * 64 + hi * 32];
  float dot = 0.f;
#pragma unroll
  for (int i = 0; i < 4; ++i) {
    uint4 kv = kr[i];
    const float* q8 = qp + i * 8;
    dot += b2f_lo(kv.x) * q8[0] + b2f_hi(kv.x) * q8[1]
         + b2f_lo(kv.y) * q8[2] + b2f_hi(kv.y) * q8[3]
         + b2f_lo(kv.z) * q8[4] + b2f_hi(kv.z) * q8[5]
         + b2f_lo(kv.w) * q8[6] + b2f_hi(kv.w) * q8[7];
  }
  dot += __shfl_xor(dot, 32);
  if (hi == 0) sc[h][k] = dot * 0.125f;
  __syncthreads();
  // softmax (each lane redundantly over its head's 32 scores — LDS broadcast reads)
  float w[KNB];
  float mx = -1e30f;
#pragma unroll
  for (int i = 0; i < KNB; ++i) { w[i] = sc[h][i]; mx = fmaxf(mx, w[i]); }
  float sum = 0.f;
#pragma unroll
  for (int i = 0; i < KNB; ++i) { w[i] = __expf(w[i] - mx); sum += w[i]; }
  float inv = 1.f / sum;
  // phase 2: lane = dim d; V loads are 128B/wave coalesced
  float acc = 0.f;
#pragma unroll
  for (int i = 0; i < KNB; ++i)
    acc += w[i] * __bfloat162float(Vb[(size_t)ridx[i] * D_ + h * 64 + lane]);
  acc *= inv;
  out[((size_t)(b * S_ + p + 1)) * D_ + h * 64 + lane] = __float2bfloat16(acc);
}

extern "C" void kernel_launch(void* const* d_in, const int* in_sizes, int n_in,
                              void* d_out, int out_size, void* d_ws, size_t ws_size,
                              hipStream_t stream) {
  const float* x      = (const float*)d_in[0];
  const int*   routes = (const int*)d_in[1];
  const float* qkv_w  = (const float*)d_in[2];
  const float* qkv_b  = (const float*)d_in[3];
  const float* proj_w = (const float*)d_in[4];
  const float* proj_b = (const float*)d_in[5];
  const float* ln1_w  = (const float*)d_in[6];
  const float* ln1_b  = (const float*)d_in[7];
  const float* ln2_w  = (const float*)d_in[8];
  const float* ln2_b  = (const float*)d_in[9];
  const float* mlp_w1 = (const float*)d_in[10];
  const float* mlp_b1 = (const float*)d_in[11];
  const float* mlp_w2 = (const float*)d_in[12];
  const float* mlp_b2 = (const float*)d_in[13];
  float* out = (float*)d_out;

  // workspace layout (~52.5 MB)
  bf16* qkvw_t  = (bf16*)d_ws;                       // [2304][768]
  bf16* projw_t = qkvw_t + 2304 * 768;               // [768][768]
  bf16* mlpw1_t = projw_t + 768 * 768;               // [3072][768]
  bf16* mlpw2_t = mlpw1_t + 3072 * 768;              // [768][3072]
  bf16* xnA     = mlpw2_t + 768 * 3072;              // [4224][768]
  bf16* qkvbuf  = xnA + (size_t)MPAD * 768;          // [3][B][S][768] s-major
  bf16* attn    = qkvbuf + (size_t)3 * B_ * S_ * 768;  // [4224][768]
  bf16* h2      = attn + (size_t)MPAD * 768;         // [4224][768]
  bf16* g       = xnA;  // alias [xnA..into attn): 4224*3072 elems, all dead by mlp1

  wt_conv<768, 2304><<<dim3(24, 72), 256, 0, stream>>>(qkv_w, qkvw_t);
  wt_conv<768, 768><<<dim3(24, 24), 256, 0, stream>>>(proj_w, projw_t);
  wt_conv<768, 3072><<<dim3(24, 96), 256, 0, stream>>>(mlp_w1, mlpw1_t);
  wt_conv<3072, 768><<<dim3(96, 24), 256, 0, stream>>>(mlp_w2, mlpw2_t);

  ln_kernel<<<M_, 256, 0, stream>>>(x, ln1_w, ln1_b, xnA);

  gemm_bf16<2304, 768, 768, 0><<<dim3(33, 18, 1), 256, 0, stream>>>(xnA, qkvw_t, qkv_b, qkvbuf);

  cls_attn<<<B_ * H_, 256, 0, stream>>>(qkvbuf, attn);
  routed_attn<<<B_ * P_, 768, 0, stream>>>(qkvbuf, routes, attn);

  // proj: out = x + proj_b + attn @ proj_w   (split-K x4, atomic f32)
  init_out_xb<<<(M_ * D_) / 1024, 256, 0, stream>>>(x, proj_b, out);
  gemm_bf16<768, 768, 192, 3><<<dim3(33, 6, 4), 256, 0, stream>>>(attn, projw_t, nullptr, out);

  ln_kernel<<<M_, 256, 0, stream>>>(out, ln2_w, ln2_b, h2);

  gemm_bf16<3072, 768, 768, 2><<<dim3(33, 24, 1), 256, 0, stream>>>(h2, mlpw1_t, mlp_b1, g);

  // mlp2: out += mlp_b2 + g @ mlp_w2   (split-K x4, atomic f32)
  add_bias_ip<<<(M_ * D_) / 1024, 256, 0, stream>>>(out, mlp_b2);
  gemm_bf16<768, 3072, 768, 3><<<dim3(33, 6, 4), 256, 0, stream>>>(g, mlpw2_t, nullptr, out);
}

// Round 3
// 377.786 us; speedup vs baseline: 1.3636x; 1.3636x over previous
//
#include <hip/hip_runtime.h>
#include <hip/hip_bf16.h>

using bf16 = __hip_bfloat16;
using s8v  = __attribute__((ext_vector_type(8))) short;
using f4v  = __attribute__((ext_vector_type(4))) float;

constexpr int B_   = 4;
constexpr int P_   = 1024;
constexpr int KNB  = 32;
constexpr int D_   = 768;
constexpr int H_   = 12;
constexpr int S_   = P_ + 1;    // 1025
constexpr int M_   = B_ * S_;   // 4100
constexpr int MPAD = 4224;      // 33 * 128

#define DEVI static __device__ __forceinline__

DEVI float b2f_lo(unsigned u) { return __builtin_bit_cast(float, u << 16); }
DEVI float b2f_hi(unsigned u) { return __builtin_bit_cast(float, u & 0xffff0000u); }
DEVI unsigned short f2bu(float f) {
  return __builtin_bit_cast(unsigned short, __float2bfloat16(f));
}

// ---------------- weight fp32 (K x N) -> bf16 transposed (N x K) ----------------
template<int KK, int NN>
__global__ __launch_bounds__(256)
void wt_conv(const float* __restrict__ W, bf16* __restrict__ Wt) {
  __shared__ float t[32][33];
  int bk = blockIdx.x * 32, bn = blockIdx.y * 32;
  int tx = threadIdx.x & 31, ty = threadIdx.x >> 5;  // ty in 0..7
#pragma unroll
  for (int i = 0; i < 32; i += 8)
    t[ty + i][tx] = W[(size_t)(bk + ty + i) * NN + bn + tx];
  __syncthreads();
#pragma unroll
  for (int i = 0; i < 32; i += 8)
    Wt[(size_t)(bn + ty + i) * KK + bk + tx] = __float2bfloat16(t[tx][ty + i]);
}

// ---------------- LayerNorm fp32 -> bf16 (row = 768) ----------------
__global__ __launch_bounds__(256)
void ln_kernel(const float* __restrict__ x, const float* __restrict__ w,
               const float* __restrict__ b, bf16* __restrict__ out) {
  int row = blockIdx.x;
  const float* xr = x + (size_t)row * D_;
  int t = threadIdx.x;
  float v0 = xr[t], v1 = xr[t + 256], v2 = xr[t + 512];
  float s = v0 + v1 + v2;
  float ss = v0 * v0 + v1 * v1 + v2 * v2;
#pragma unroll
  for (int o = 32; o; o >>= 1) { s += __shfl_xor(s, o); ss += __shfl_xor(ss, o); }
  __shared__ float sm[4], sv[4];
  if ((t & 63) == 0) { sm[t >> 6] = s; sv[t >> 6] = ss; }
  __syncthreads();
  float S = sm[0] + sm[1] + sm[2] + sm[3];
  float SS = sv[0] + sv[1] + sv[2] + sv[3];
  float mean = S * (1.f / D_);
  float var  = SS * (1.f / D_) - mean * mean;
  float inv  = rsqrtf(var + 1e-5f);
  bf16* orow = out + (size_t)row * D_;
  orow[t]       = __float2bfloat16((v0 - mean) * inv * w[t]       + b[t]);
  orow[t + 256] = __float2bfloat16((v1 - mean) * inv * w[t + 256] + b[t + 256]);
  orow[t + 512] = __float2bfloat16((v2 - mean) * inv * w[t + 512] + b[t + 512]);
}

// ---------------- bf16 GEMM: C = A(MPADxK) * Bt(NxK)^T, tile BM x 128 ----------------
// MODE 0: + bias -> scatter to QKV buffer [3][B][S][768] bf16
// MODE 1: + bias + resid(fp32) -> fp32 dst [M][N]
// MODE 2: + bias -> gelu(exact) -> bf16 dst [MPAD][N]
template<int BM, int N, int K, int MODE>
__global__ __launch_bounds__(256)
void gemm_bf16(const bf16* __restrict__ A, const bf16* __restrict__ Bt,
               const float* __restrict__ bias, const float* __restrict__ resid,
               void* __restrict__ dst) {
  constexpr int MR = BM / 32;              // m-fragments per wave (wave rows = MR*16)
  __shared__ bf16 ldsA[2][BM * 32];
  __shared__ bf16 ldsB[2][128 * 32];
  const int tm = blockIdx.x, tn = blockIdx.y;
  const int tid = threadIdx.x;
  const int wid = tid >> 6, lane = tid & 63;
  const int wr = wid >> 1, wc = wid & 1;

  auto stage = [&](int bufi, int step) {
    const int k0 = step * 32;
#pragma unroll
    for (int i = 0; i < BM / 64; ++i) {
      int c = wid * 64 + i * 256 + lane;
      int r = c >> 2, slot = c & 3;
      int gs = slot ^ ((r >> 1) & 3);  // inverse-swizzled global source (rule 21)
      const bf16* ga = A + (size_t)(tm * BM + r) * K + k0 + gs * 8;
      bf16* la = &ldsA[bufi][(wid * 64 + i * 256) * 8];
      __builtin_amdgcn_global_load_lds(
          (__attribute__((address_space(1))) void*)ga,
          (__attribute__((address_space(3))) void*)la, 16, 0, 0);
    }
#pragma unroll
    for (int i = 0; i < 2; ++i) {
      int c = wid * 64 + i * 256 + lane;
      int r = c >> 2, slot = c & 3;
      int gs = slot ^ ((r >> 1) & 3);
      const bf16* ga = Bt + (size_t)(tn * 128 + r) * K + k0 + gs * 8;
      bf16* la = &ldsB[bufi][(wid * 64 + i * 256) * 8];
      __builtin_amdgcn_global_load_lds(
          (__attribute__((address_space(1))) void*)ga,
          (__attribute__((address_space(3))) void*)la, 16, 0, 0);
    }
  };

  f4v acc[MR][4] = {};

  stage(0, 0);
  __syncthreads();
  int buf = 0;
  const int nk = K / 32;
  for (int kt = 0; kt < nk; ++kt) {
    if (kt + 1 < nk) stage(buf ^ 1, kt + 1);
    s8v af[MR], bfv[4];
#pragma unroll
    for (int m = 0; m < MR; ++m) {
      int row = wr * (MR * 16) + m * 16 + (lane & 15);
      int slot = (lane >> 4) ^ ((row >> 1) & 3);
      af[m] = *(const s8v*)&ldsA[buf][row * 32 + slot * 8];
    }
#pragma unroll
    for (int n = 0; n < 4; ++n) {
      int row = wc * 64 + n * 16 + (lane & 15);
      int slot = (lane >> 4) ^ ((row >> 1) & 3);
      bfv[n] = *(const s8v*)&ldsB[buf][row * 32 + slot * 8];
    }
#pragma unroll
    for (int m = 0; m < MR; ++m)
#pragma unroll
      for (int n = 0; n < 4; ++n)
        acc[m][n] = __builtin_amdgcn_mfma_f32_16x16x32_bf16(af[m], bfv[n], acc[m][n], 0, 0, 0);
    __syncthreads();
    buf ^= 1;
  }

#pragma unroll
  for (int m = 0; m < MR; ++m)
#pragma unroll
    for (int n = 0; n < 4; ++n)
#pragma unroll
      for (int j = 0; j < 4; ++j) {
        int row = tm * BM + wr * (MR * 16) + m * 16 + (lane >> 4) * 4 + j;
        int col = tn * 128 + wc * 64 + n * 16 + (lane & 15);   // C: col=l&15 (m89)
        float v = acc[m][n][j];
        if (MODE == 0) {
          if (row < M_) {
            float val = v + bias[col];
            int which = col / 768, rem = col % 768;
            int bb = row / S_, s = row % S_;
            ((bf16*)dst)[((size_t)(which * B_ + bb) * S_ + s) * 768 + rem] =
                __float2bfloat16(val);
          }
        } else if (MODE == 1) {
          if (row < M_) {
            float val = v + bias[col] + resid[(size_t)row * N + col];
            ((float*)dst)[(size_t)row * N + col] = val;
          }
        } else {
          float val = v + bias[col];
          val = 0.5f * val * (1.f + erff(val * 0.70710678f));
          ((bf16*)dst)[(size_t)row * N + col] = __float2bfloat16(val);
        }
      }
}

// ---------------- cls-token attention, flash-split over 4 S-chunks ----------------
__global__ __launch_bounds__(256)
void cls_partial(const bf16* __restrict__ QKV, float* __restrict__ part) {
  int bh = blockIdx.x, c = blockIdx.y;
  int b = bh / H_, h = bh % H_;
  const bf16* q  = QKV + ((size_t)(0 * B_ + b) * S_) * D_ + h * 64;
  const bf16* Kr = QKV + ((size_t)(1 * B_ + b) * S_) * D_ + h * 64;
  const bf16* Vr = QKV + ((size_t)(2 * B_ + b) * S_) * D_ + h * 64;
  int k0 = c * 256, kn = (c == 3) ? 257 : 256;
  __shared__ float qf[64];
  __shared__ float sc[257];
  __shared__ float red[4];
  __shared__ float pv[4][64];
  int t = threadIdx.x;
  if (t < 64) qf[t] = __bfloat162float(q[t]);
  __syncthreads();
  for (int kk = t; kk < kn; kk += 256) {
    const uint4* k4 = (const uint4*)(Kr + (size_t)(k0 + kk) * D_);
    float s = 0.f;
#pragma unroll
    for (int i = 0; i < 8; ++i) {
      uint4 kv = k4[i];
      const float* q8 = &qf[i * 8];
      s += b2f_lo(kv.x) * q8[0] + b2f_hi(kv.x) * q8[1]
         + b2f_lo(kv.y) * q8[2] + b2f_hi(kv.y) * q8[3]
         + b2f_lo(kv.z) * q8[4] + b2f_hi(kv.z) * q8[5]
         + b2f_lo(kv.w) * q8[6] + b2f_hi(kv.w) * q8[7];
    }
    sc[kk] = s * 0.125f;
  }
  __syncthreads();
  float mx = -1e30f;
  for (int kk = t; kk < kn; kk += 256) mx = fmaxf(mx, sc[kk]);
#pragma unroll
  for (int o = 32; o; o >>= 1) mx = fmaxf(mx, __shfl_xor(mx, o));
  if ((t & 63) == 0) red[t >> 6] = mx;
  __syncthreads();
  float M = fmaxf(fmaxf(red[0], red[1]), fmaxf(red[2], red[3]));
  __syncthreads();
  float sum = 0.f;
  for (int kk = t; kk < kn; kk += 256) { float e = __expf(sc[kk] - M); sc[kk] = e; sum += e; }
#pragma unroll
  for (int o = 32; o; o >>= 1) sum += __shfl_xor(sum, o);
  if ((t & 63) == 0) red[t >> 6] = sum;
  __syncthreads();
  float L = red[0] + red[1] + red[2] + red[3];
  int d = t & 63, kg = t >> 6;
  float acc = 0.f;
  for (int kk = kg; kk < kn; kk += 4)
    acc += sc[kk] * __bfloat162float(Vr[(size_t)(k0 + kk) * D_ + d]);
  pv[kg][d] = acc;
  __syncthreads();
  float* pp = part + ((size_t)bh * 4 + c) * 68;
  if (t < 64) pp[4 + t] = pv[0][t] + pv[1][t] + pv[2][t] + pv[3][t];
  else if (t == 64) pp[0] = M;
  else if (t == 65) pp[1] = L;
}

__global__ __launch_bounds__(64)
void cls_combine(const float* __restrict__ part, bf16* __restrict__ out) {
  int bh = blockIdx.x, t = threadIdx.x;
  const float* pp = part + (size_t)bh * 4 * 68;
  float m0 = pp[0], m1 = pp[68], m2 = pp[136], m3 = pp[204];
  float M = fmaxf(fmaxf(m0, m1), fmaxf(m2, m3));
  float e0 = __expf(m0 - M), e1 = __expf(m1 - M), e2 = __expf(m2 - M), e3 = __expf(m3 - M);
  float L = pp[1] * e0 + pp[69] * e1 + pp[137] * e2 + pp[205] * e3;
  float o = pp[4 + t] * e0 + pp[72 + t] * e1 + pp[140 + t] * e2 + pp[208 + t] * e3;
  int b = bh / H_, h = bh % H_;
  out[(size_t)(b * S_) * D_ + h * 64 + t] = __float2bfloat16(o / L);
}

// ---------------- routed attention: one wave per (b,p,h), no barriers ----------------
__global__ __launch_bounds__(256)
void routed_attn(const bf16* __restrict__ QKV, const int* __restrict__ routes,
                 bf16* __restrict__ out) {
  int unit = blockIdx.x * 4 + (threadIdx.x >> 6);  // (b*P + p)*H + h ; b slowest
  int lane = threadIdx.x & 63;
  int h = unit % H_;
  int bp = unit / H_;
  int p = bp % P_, b = bp / P_;

  int k = lane & 31, hi = lane >> 5;
  int r = routes[p * KNB + k] + 1;                 // gathered token row

  const bf16* Qp = QKV + ((size_t)(0 * B_ + b) * S_ + (p + 1)) * D_ + h * 64 + hi * 32;
  const bf16* Kb = QKV + ((size_t)(1 * B_ + b) * S_) * D_;
  const bf16* Vb = QKV + ((size_t)(2 * B_ + b) * S_) * D_;

  // phase 1: 32-dim half-dot per lane
  const uint4* q4 = (const uint4*)Qp;
  const uint4* k4 = (const uint4*)(Kb + (size_t)r * D_ + h * 64 + hi * 32);
  float dot = 0.f;
#pragma unroll
  for (int i = 0; i < 4; ++i) {
    uint4 qv = q4[i], kv = k4[i];
    dot += b2f_lo(kv.x) * b2f_lo(qv.x) + b2f_hi(kv.x) * b2f_hi(qv.x)
         + b2f_lo(kv.y) * b2f_lo(qv.y) + b2f_hi(kv.y) * b2f_hi(qv.y)
         + b2f_lo(kv.z) * b2f_lo(qv.z) + b2f_hi(kv.z) * b2f_hi(qv.z)
         + b2f_lo(kv.w) * b2f_lo(qv.w) + b2f_hi(kv.w) * b2f_hi(qv.w);
  }
  dot += __shfl_xor(dot, 32);
  float sc = dot * 0.125f;

  // softmax over the 32 keys (both halves hold identical values)
  float mx = sc;
#pragma unroll
  for (int o = 16; o; o >>= 1) mx = fmaxf(mx, __shfl_xor(mx, o));
  float w = __expf(sc - mx);
  float sum = w;
#pragma unroll
  for (int o = 16; o; o >>= 1) sum += __shfl_xor(sum, o);
  float inv = 1.f / sum;

  // phase 2: lane = (key-octet, dim-chunk); uint4 V loads
  int c = lane & 7, kr0 = lane >> 3;
  float acc[8] = {};
#pragma unroll
  for (int j = 0; j < 4; ++j) {
    int kj = (kr0 & 7) + 8 * j;          // 0..31
    float wj = __shfl(w, kj);
    int rj = __shfl(r, kj);
    uint4 vv = *(const uint4*)(Vb + (size_t)rj * D_ + h * 64 + c * 8);
    acc[0] += wj * b2f_lo(vv.x); acc[1] += wj * b2f_hi(vv.x);
    acc[2] += wj * b2f_lo(vv.y); acc[3] += wj * b2f_hi(vv.y);
    acc[4] += wj * b2f_lo(vv.z); acc[5] += wj * b2f_hi(vv.z);
    acc[6] += wj * b2f_lo(vv.w); acc[7] += wj * b2f_hi(vv.w);
  }
#pragma unroll
  for (int s = 8; s < 64; s <<= 1)
#pragma unroll
    for (int d = 0; d < 8; ++d) acc[d] += __shfl_xor(acc[d], s);

  if (lane < 8) {
    s8v o;
#pragma unroll
    for (int d = 0; d < 8; ++d) o[d] = (short)f2bu(acc[d] * inv);
    *(s8v*)(out + ((size_t)(b * S_ + p + 1)) * D_ + h * 64 + c * 8) = o;
  }
}

extern "C" void kernel_launch(void* const* d_in, const int* in_sizes, int n_in,
                              void* d_out, int out_size, void* d_ws, size_t ws_size,
                              hipStream_t stream) {
  const float* x      = (const float*)d_in[0];
  const int*   routes = (const int*)d_in[1];
  const float* qkv_w  = (const float*)d_in[2];
  const float* qkv_b  = (const float*)d_in[3];
  const float* proj_w = (const float*)d_in[4];
  const float* proj_b = (const float*)d_in[5];
  const float* ln1_w  = (const float*)d_in[6];
  const float* ln1_b  = (const float*)d_in[7];
  const float* ln2_w  = (const float*)d_in[8];
  const float* ln2_b  = (const float*)d_in[9];
  const float* mlp_w1 = (const float*)d_in[10];
  const float* mlp_b1 = (const float*)d_in[11];
  const float* mlp_w2 = (const float*)d_in[12];
  const float* mlp_b2 = (const float*)d_in[13];
  float* out = (float*)d_out;

  // workspace layout (~52.5 MB, same footprint as R1-proven)
  bf16* qkvw_t  = (bf16*)d_ws;                       // [2304][768]
  bf16* projw_t = qkvw_t + 2304 * 768;               // [768][768]
  bf16* mlpw1_t = projw_t + 768 * 768;               // [3072][768]
  bf16* mlpw2_t = mlpw1_t + 3072 * 768;              // [768][3072]
  bf16* xnA     = mlpw2_t + 768 * 3072;              // [4224][768]
  bf16* qkvbuf  = xnA + (size_t)MPAD * 768;          // [3][B][S][768] s-major
  bf16* attn    = qkvbuf + (size_t)3 * B_ * S_ * 768;  // [4224][768]
  bf16* h2      = attn + (size_t)MPAD * 768;         // [4224][768]
  bf16* g       = xnA;  // alias: 4224*3072 elems; spans xnA+qkvbuf+0.6MB of attn (all dead)
  float* clsp   = (float*)(attn + (size_t)M_ * 768); // cls partials in attn's row padding (52KB)

  wt_conv<768, 2304><<<dim3(24, 72), 256, 0, stream>>>(qkv_w, qkvw_t);
  wt_conv<768, 768><<<dim3(24, 24), 256, 0, stream>>>(proj_w, projw_t);
  wt_conv<768, 3072><<<dim3(24, 96), 256, 0, stream>>>(mlp_w1, mlpw1_t);
  wt_conv<3072, 768><<<dim3(96, 24), 256, 0, stream>>>(mlp_w2, mlpw2_t);

  ln_kernel<<<M_, 256, 0, stream>>>(x, ln1_w, ln1_b, xnA);

  gemm_bf16<128, 2304, 768, 0><<<dim3(33, 18), 256, 0, stream>>>(xnA, qkvw_t, qkv_b, nullptr, qkvbuf);

  routed_attn<<<(B_ * P_ * H_) / 4, 256, 0, stream>>>(qkvbuf, routes, attn);
  cls_partial<<<dim3(B_ * H_, 4), 256, 0, stream>>>(qkvbuf, clsp);
  cls_combine<<<B_ * H_, 64, 0, stream>>>(clsp, attn);

  // proj: out = x + proj_b + attn @ proj_w   (BM=64 tile -> 396 blocks)
  gemm_bf16<64, 768, 768, 1><<<dim3(66, 6), 256, 0, stream>>>(attn, projw_t, proj_b, x, out);

  ln_kernel<<<M_, 256, 0, stream>>>(out, ln2_w, ln2_b, h2);

  gemm_bf16<128, 3072, 768, 2><<<dim3(33, 24), 256, 0, stream>>>(h2, mlpw1_t, mlp_b1, nullptr, g);

  // mlp2: out = out + mlp_b2 + g @ mlp_w2   (BM=64 tile, K=3072 -> 396 blocks)
  gemm_bf16<64, 768, 3072, 1><<<dim3(66, 6), 256, 0, stream>>>(g, mlpw2_t, mlp_b2, out, out);
}

// Round 4
// 361.651 us; speedup vs baseline: 1.4244x; 1.0446x over previous
//
#include <hip/hip_runtime.h>
#include <hip/hip_bf16.h>

using bf16 = __hip_bfloat16;
using s8v  = __attribute__((ext_vector_type(8))) short;
using f4v  = __attribute__((ext_vector_type(4))) float;

constexpr int B_   = 4;
constexpr int P_   = 1024;
constexpr int KNB  = 32;
constexpr int D_   = 768;
constexpr int H_   = 12;
constexpr int S_   = P_ + 1;    // 1025
constexpr int M_   = B_ * S_;   // 4100
constexpr int MPAD = 4224;      // 33 * 128

#define DEVI static __device__ __forceinline__
#define WAITVM(N) asm volatile("s_waitcnt vmcnt(" #N ")" ::: "memory")
#define MEMFENCE  asm volatile("" ::: "memory")

DEVI float b2f_lo(unsigned u) { return __builtin_bit_cast(float, u << 16); }
DEVI float b2f_hi(unsigned u) { return __builtin_bit_cast(float, u & 0xffff0000u); }
DEVI unsigned short f2bu(float f) {
  return __builtin_bit_cast(unsigned short, __float2bfloat16(f));
}

// ---------------- weight fp32 (K x N) -> bf16 transposed (N x K) ----------------
template<int KK, int NN>
__global__ __launch_bounds__(256)
void wt_conv(const float* __restrict__ W, bf16* __restrict__ Wt) {
  __shared__ float t[32][33];
  int bk = blockIdx.x * 32, bn = blockIdx.y * 32;
  int tx = threadIdx.x & 31, ty = threadIdx.x >> 5;  // ty in 0..7
#pragma unroll
  for (int i = 0; i < 32; i += 8)
    t[ty + i][tx] = W[(size_t)(bk + ty + i) * NN + bn + tx];
  __syncthreads();
#pragma unroll
  for (int i = 0; i < 32; i += 8)
    Wt[(size_t)(bn + ty + i) * KK + bk + tx] = __float2bfloat16(t[tx][ty + i]);
}

// ---------------- LayerNorm fp32 -> bf16 (row = 768) ----------------
__global__ __launch_bounds__(256)
void ln_kernel(const float* __restrict__ x, const float* __restrict__ w,
               const float* __restrict__ b, bf16* __restrict__ out) {
  int row = blockIdx.x;
  const float* xr = x + (size_t)row * D_;
  int t = threadIdx.x;
  float v0 = xr[t], v1 = xr[t + 256], v2 = xr[t + 512];
  float s = v0 + v1 + v2;
  float ss = v0 * v0 + v1 * v1 + v2 * v2;
#pragma unroll
  for (int o = 32; o; o >>= 1) { s += __shfl_xor(s, o); ss += __shfl_xor(ss, o); }
  __shared__ float sm[4], sv[4];
  if ((t & 63) == 0) { sm[t >> 6] = s; sv[t >> 6] = ss; }
  __syncthreads();
  float S = sm[0] + sm[1] + sm[2] + sm[3];
  float SS = sv[0] + sv[1] + sv[2] + sv[3];
  float mean = S * (1.f / D_);
  float var  = SS * (1.f / D_) - mean * mean;
  float inv  = rsqrtf(var + 1e-5f);
  bf16* orow = out + (size_t)row * D_;
  orow[t]       = __float2bfloat16((v0 - mean) * inv * w[t]       + b[t]);
  orow[t + 256] = __float2bfloat16((v1 - mean) * inv * w[t + 256] + b[t + 256]);
  orow[t + 512] = __float2bfloat16((v2 - mean) * inv * w[t + 512] + b[t + 512]);
}

// ---------------- bf16 GEMM, depth-4 counted-vmcnt pipeline ----------------
// C = A(MPADxK) * Bt(NxK)^T, tile BM x 128, 1D grid with bijective XCD swizzle.
// MODE 0: + bias -> scatter to QKV buffer [3][B][S][768] bf16
// MODE 1: + bias + resid(fp32) -> fp32 dst [M][N]
// MODE 2: + bias -> gelu(exact) -> bf16 dst [MPAD][N]
template<int BM, int N, int K, int MODE>
__global__ __launch_bounds__(256)
void gemm_bf16(const bf16* __restrict__ A, const bf16* __restrict__ Bt,
               const float* __restrict__ bias, const float* __restrict__ resid,
               void* __restrict__ dst) {
  constexpr int MR   = BM / 32;        // m-fragments per wave (wave rows = MR*16)
  constexpr int LPS  = BM / 64 + 2;    // global_load_lds per wave per stage
  constexpr int TN   = N / 128;
  constexpr int NBLK = (MPAD / BM) * TN;
  __shared__ bf16 ldsA[4][BM * 32];
  __shared__ bf16 ldsB[4][128 * 32];

  // bijective XCD-chunked remap (m204): XCD k gets a contiguous tm-major chunk
  int bid = blockIdx.x;
  constexpr int NQ = NBLK >> 3, NR = NBLK & 7;
  int xcd = bid & 7, off = bid >> 3;
  int swz = (xcd < NR ? xcd * (NQ + 1) : NR * (NQ + 1) + (xcd - NR) * NQ) + off;
  const int tm = swz / TN, tn = swz % TN;

  const int tid = threadIdx.x;
  const int wid = tid >> 6, lane = tid & 63;
  const int wr = wid >> 1, wc = wid & 1;

  auto stage = [&](int bufi, int step) {
    const int k0 = step * 32;
#pragma unroll
    for (int i = 0; i < BM / 64; ++i) {
      int c = wid * 64 + i * 256 + lane;
      int r = c >> 2, slot = c & 3;
      int gs = slot ^ ((r >> 1) & 3);  // inverse-swizzled global source (rule 21)
      const bf16* ga = A + (size_t)(tm * BM + r) * K + k0 + gs * 8;
      bf16* la = &ldsA[bufi][(wid * 64 + i * 256) * 8];
      __builtin_amdgcn_global_load_lds(
          (__attribute__((address_space(1))) void*)ga,
          (__attribute__((address_space(3))) void*)la, 16, 0, 0);
    }
#pragma unroll
    for (int i = 0; i < 2; ++i) {
      int c = wid * 64 + i * 256 + lane;
      int r = c >> 2, slot = c & 3;
      int gs = slot ^ ((r >> 1) & 3);
      const bf16* ga = Bt + (size_t)(tn * 128 + r) * K + k0 + gs * 8;
      bf16* la = &ldsB[bufi][(wid * 64 + i * 256) * 8];
      __builtin_amdgcn_global_load_lds(
          (__attribute__((address_space(1))) void*)ga,
          (__attribute__((address_space(3))) void*)la, 16, 0, 0);
    }
  };

  f4v acc[MR][4] = {};
  const int nk = K / 32;

  stage(0, 0); stage(1, 1); stage(2, 2);   // 3 stages in flight (3*LPS vm ops)

#pragma unroll 4
  for (int kt = 0; kt < nk; ++kt) {
    const int rem = nk - kt;  // stages in flight before this wait = min(3, rem)
    if (rem > 2) {            // wait for oldest of 3 -> leave 2*LPS outstanding
      if constexpr (LPS == 4) WAITVM(8); else WAITVM(6);
    } else if (rem == 2) {
      if constexpr (LPS == 4) WAITVM(4); else WAITVM(3);
    } else {
      WAITVM(0);
    }
    __builtin_amdgcn_s_barrier();   // stage(kt) visible to all; buf[(kt+3)&3] free
    MEMFENCE;
    if (kt + 3 < nk) stage((kt + 3) & 3, kt + 3);  // 3-iteration runway

    const int cur = kt & 3;
    s8v af[MR], bfv[4];
#pragma unroll
    for (int m = 0; m < MR; ++m) {
      int row = wr * (MR * 16) + m * 16 + (lane & 15);
      int slot = (lane >> 4) ^ ((row >> 1) & 3);
      af[m] = *(const s8v*)&ldsA[cur][row * 32 + slot * 8];
    }
#pragma unroll
    for (int n = 0; n < 4; ++n) {
      int row = wc * 64 + n * 16 + (lane & 15);
      int slot = (lane >> 4) ^ ((row >> 1) & 3);
      bfv[n] = *(const s8v*)&ldsB[cur][row * 32 + slot * 8];
    }
#pragma unroll
    for (int m = 0; m < MR; ++m)
#pragma unroll
      for (int n = 0; n < 4; ++n)
        acc[m][n] = __builtin_amdgcn_mfma_f32_16x16x32_bf16(af[m], bfv[n], acc[m][n], 0, 0, 0);
  }

#pragma unroll
  for (int m = 0; m < MR; ++m)
#pragma unroll
    for (int n = 0; n < 4; ++n)
#pragma unroll
      for (int j = 0; j < 4; ++j) {
        int row = tm * BM + wr * (MR * 16) + m * 16 + (lane >> 4) * 4 + j;
        int col = tn * 128 + wc * 64 + n * 16 + (lane & 15);   // C: col=l&15 (m89)
        float v = acc[m][n][j];
        if (MODE == 0) {
          if (row < M_) {
            float val = v + bias[col];
            int which = col / 768, rem2 = col % 768;
            int bb = row / S_, s = row % S_;
            ((bf16*)dst)[((size_t)(which * B_ + bb) * S_ + s) * 768 + rem2] =
                __float2bfloat16(val);
          }
        } else if (MODE == 1) {
          if (row < M_) {
            float val = v + bias[col] + resid[(size_t)row * N + col];
            ((float*)dst)[(size_t)row * N + col] = val;
          }
        } else {
          float val = v + bias[col];
          val = 0.5f * val * (1.f + erff(val * 0.70710678f));
          ((bf16*)dst)[(size_t)row * N + col] = __float2bfloat16(val);
        }
      }
}

// ---------------- cls-token attention, flash-split over 4 S-chunks ----------------
__global__ __launch_bounds__(256)
void cls_partial(const bf16* __restrict__ QKV, float* __restrict__ part) {
  int bh = blockIdx.x, c = blockIdx.y;
  int b = bh / H_, h = bh % H_;
  const bf16* q  = QKV + ((size_t)(0 * B_ + b) * S_) * D_ + h * 64;
  const bf16* Kr = QKV + ((size_t)(1 * B_ + b) * S_) * D_ + h * 64;
  const bf16* Vr = QKV + ((size_t)(2 * B_ + b) * S_) * D_ + h * 64;
  int k0 = c * 256, kn = (c == 3) ? 257 : 256;
  __shared__ float qf[64];
  __shared__ float sc[257];
  __shared__ float red[4];
  __shared__ float pv[4][64];
  int t = threadIdx.x;
  if (t < 64) qf[t] = __bfloat162float(q[t]);
  __syncthreads();
  for (int kk = t; kk < kn; kk += 256) {
    const uint4* k4 = (const uint4*)(Kr + (size_t)(k0 + kk) * D_);
    float s = 0.f;
#pragma unroll
    for (int i = 0; i < 8; ++i) {
      uint4 kv = k4[i];
      const float* q8 = &qf[i * 8];
      s += b2f_lo(kv.x) * q8[0] + b2f_hi(kv.x) * q8[1]
         + b2f_lo(kv.y) * q8[2] + b2f_hi(kv.y) * q8[3]
         + b2f_lo(kv.z) * q8[4] + b2f_hi(kv.z) * q8[5]
         + b2f_lo(kv.w) * q8[6] + b2f_hi(kv.w) * q8[7];
    }
    sc[kk] = s * 0.125f;
  }
  __syncthreads();
  float mx = -1e30f;
  for (int kk = t; kk < kn; kk += 256) mx = fmaxf(mx, sc[kk]);
#pragma unroll
  for (int o = 32; o; o >>= 1) mx = fmaxf(mx, __shfl_xor(mx, o));
  if ((t & 63) == 0) red[t >> 6] = mx;
  __syncthreads();
  float M = fmaxf(fmaxf(red[0], red[1]), fmaxf(red[2], red[3]));
  __syncthreads();
  float sum = 0.f;
  for (int kk = t; kk < kn; kk += 256) { float e = __expf(sc[kk] - M); sc[kk] = e; sum += e; }
#pragma unroll
  for (int o = 32; o; o >>= 1) sum += __shfl_xor(sum, o);
  if ((t & 63) == 0) red[t >> 6] = sum;
  __syncthreads();
  float L = red[0] + red[1] + red[2] + red[3];
  int d = t & 63, kg = t >> 6;
  float acc = 0.f;
  for (int kk = kg; kk < kn; kk += 4)
    acc += sc[kk] * __bfloat162float(Vr[(size_t)(k0 + kk) * D_ + d]);
  pv[kg][d] = acc;
  __syncthreads();
  float* pp = part + ((size_t)bh * 4 + c) * 68;
  if (t < 64) pp[4 + t] = pv[0][t] + pv[1][t] + pv[2][t] + pv[3][t];
  else if (t == 64) pp[0] = M;
  else if (t == 65) pp[1] = L;
}

__global__ __launch_bounds__(64)
void cls_combine(const float* __restrict__ part, bf16* __restrict__ out) {
  int bh = blockIdx.x, t = threadIdx.x;
  const float* pp = part + (size_t)bh * 4 * 68;
  float m0 = pp[0], m1 = pp[68], m2 = pp[136], m3 = pp[204];
  float M = fmaxf(fmaxf(m0, m1), fmaxf(m2, m3));
  float e0 = __expf(m0 - M), e1 = __expf(m1 - M), e2 = __expf(m2 - M), e3 = __expf(m3 - M);
  float L = pp[1] * e0 + pp[69] * e1 + pp[137] * e2 + pp[205] * e3;
  float o = pp[4 + t] * e0 + pp[72 + t] * e1 + pp[140 + t] * e2 + pp[208 + t] * e3;
  int b = bh / H_, h = bh % H_;
  out[(size_t)(b * S_) * D_ + h * 64 + t] = __float2bfloat16(o / L);
}

// ---------------- routed attention: one wave per (b,p,h), no barriers ----------------
__global__ __launch_bounds__(256)
void routed_attn(const bf16* __restrict__ QKV, const int* __restrict__ routes,
                 bf16* __restrict__ out) {
  int unit = blockIdx.x * 4 + (threadIdx.x >> 6);  // (b*P + p)*H + h ; b slowest
  int lane = threadIdx.x & 63;
  int h = unit % H_;
  int bp = unit / H_;
  int p = bp % P_, b = bp / P_;

  int k = lane & 31, hi = lane >> 5;
  int r = routes[p * KNB + k] + 1;                 // gathered token row

  const bf16* Qp = QKV + ((size_t)(0 * B_ + b) * S_ + (p + 1)) * D_ + h * 64 + hi * 32;
  const bf16* Kb = QKV + ((size_t)(1 * B_ + b) * S_) * D_;
  const bf16* Vb = QKV + ((size_t)(2 * B_ + b) * S_) * D_;

  // phase 1: 32-dim half-dot per lane
  const uint4* q4 = (const uint4*)Qp;
  const uint4* k4 = (const uint4*)(Kb + (size_t)r * D_ + h * 64 + hi * 32);
  float dot = 0.f;
#pragma unroll
  for (int i = 0; i < 4; ++i) {
    uint4 qv = q4[i], kv = k4[i];
    dot += b2f_lo(kv.x) * b2f_lo(qv.x) + b2f_hi(kv.x) * b2f_hi(qv.x)
         + b2f_lo(kv.y) * b2f_lo(qv.y) + b2f_hi(kv.y) * b2f_hi(qv.y)
         + b2f_lo(kv.z) * b2f_lo(qv.z) + b2f_hi(kv.z) * b2f_hi(qv.z)
         + b2f_lo(kv.w) * b2f_lo(qv.w) + b2f_hi(kv.w) * b2f_hi(qv.w);
  }
  dot += __shfl_xor(dot, 32);
  float sc = dot * 0.125f;

  // softmax over the 32 keys (both halves hold identical values)
  float mx = sc;
#pragma unroll
  for (int o = 16; o; o >>= 1) mx = fmaxf(mx, __shfl_xor(mx, o));
  float w = __expf(sc - mx);
  float sum = w;
#pragma unroll
  for (int o = 16; o; o >>= 1) sum += __shfl_xor(sum, o);
  float inv = 1.f / sum;

  // phase 2: lane = (key-octet, dim-chunk); uint4 V loads
  int c = lane & 7, kr0 = lane >> 3;
  float acc[8] = {};
#pragma unroll
  for (int j = 0; j < 4; ++j) {
    int kj = (kr0 & 7) + 8 * j;          // 0..31
    float wj = __shfl(w, kj);
    int rj = __shfl(r, kj);
    uint4 vv = *(const uint4*)(Vb + (size_t)rj * D_ + h * 64 + c * 8);
    acc[0] += wj * b2f_lo(vv.x); acc[1] += wj * b2f_hi(vv.x);
    acc[2] += wj * b2f_lo(vv.y); acc[3] += wj * b2f_hi(vv.y);
    acc[4] += wj * b2f_lo(vv.z); acc[5] += wj * b2f_hi(vv.z);
    acc[6] += wj * b2f_lo(vv.w); acc[7] += wj * b2f_hi(vv.w);
  }
#pragma unroll
  for (int s = 8; s < 64; s <<= 1)
#pragma unroll
    for (int d = 0; d < 8; ++d) acc[d] += __shfl_xor(acc[d], s);

  if (lane < 8) {
    s8v o;
#pragma unroll
    for (int d = 0; d < 8; ++d) o[d] = (short)f2bu(acc[d] * inv);
    *(s8v*)(out + ((size_t)(b * S_ + p + 1)) * D_ + h * 64 + c * 8) = o;
  }
}

extern "C" void kernel_launch(void* const* d_in, const int* in_sizes, int n_in,
                              void* d_out, int out_size, void* d_ws, size_t ws_size,
                              hipStream_t stream) {
  const float* x      = (const float*)d_in[0];
  const int*   routes = (const int*)d_in[1];
  const float* qkv_w  = (const float*)d_in[2];
  const float* qkv_b  = (const float*)d_in[3];
  const float* proj_w = (const float*)d_in[4];
  const float* proj_b = (const float*)d_in[5];
  const float* ln1_w  = (const float*)d_in[6];
  const float* ln1_b  = (const float*)d_in[7];
  const float* ln2_w  = (const float*)d_in[8];
  const float* ln2_b  = (const float*)d_in[9];
  const float* mlp_w1 = (const float*)d_in[10];
  const float* mlp_b1 = (const float*)d_in[11];
  const float* mlp_w2 = (const float*)d_in[12];
  const float* mlp_b2 = (const float*)d_in[13];
  float* out = (float*)d_out;

  // workspace layout (~52.5 MB, same footprint as R2/R3-proven)
  bf16* qkvw_t  = (bf16*)d_ws;                       // [2304][768]
  bf16* projw_t = qkvw_t + 2304 * 768;               // [768][768]
  bf16* mlpw1_t = projw_t + 768 * 768;               // [3072][768]
  bf16* mlpw2_t = mlpw1_t + 3072 * 768;              // [768][3072]
  bf16* xnA     = mlpw2_t + 768 * 3072;              // [4224][768]
  bf16* qkvbuf  = xnA + (size_t)MPAD * 768;          // [3][B][S][768] s-major
  bf16* attn    = qkvbuf + (size_t)3 * B_ * S_ * 768;  // [4224][768]
  bf16* h2      = attn + (size_t)MPAD * 768;         // [4224][768]
  bf16* g       = xnA;  // alias: 4224*3072 elems; spans xnA+qkvbuf+0.6MB of attn (all dead)
  float* clsp   = (float*)(attn + (size_t)M_ * 768); // cls partials in attn's row padding (52KB)

  wt_conv<768, 2304><<<dim3(24, 72), 256, 0, stream>>>(qkv_w, qkvw_t);
  wt_conv<768, 768><<<dim3(24, 24), 256, 0, stream>>>(proj_w, projw_t);
  wt_conv<768, 3072><<<dim3(24, 96), 256, 0, stream>>>(mlp_w1, mlpw1_t);
  wt_conv<3072, 768><<<dim3(96, 24), 256, 0, stream>>>(mlp_w2, mlpw2_t);

  ln_kernel<<<M_, 256, 0, stream>>>(x, ln1_w, ln1_b, xnA);

  gemm_bf16<128, 2304, 768, 0><<<33 * 18, 256, 0, stream>>>(xnA, qkvw_t, qkv_b, nullptr, qkvbuf);

  routed_attn<<<(B_ * P_ * H_) / 4, 256, 0, stream>>>(qkvbuf, routes, attn);
  cls_partial<<<dim3(B_ * H_, 4), 256, 0, stream>>>(qkvbuf, clsp);
  cls_combine<<<B_ * H_, 64, 0, stream>>>(clsp, attn);

  // proj: out = x + proj_b + attn @ proj_w   (BM=64 -> 396 blocks)
  gemm_bf16<64, 768, 768, 1><<<66 * 6, 256, 0, stream>>>(attn, projw_t, proj_b, x, out);

  ln_kernel<<<M_, 256, 0, stream>>>(out, ln2_w, ln2_b, h2);

  gemm_bf16<128, 3072, 768, 2><<<33 * 24, 256, 0, stream>>>(h2, mlpw1_t, mlp_b1, nullptr, g);

  // mlp2: out = out + mlp_b2 + g @ mlp_w2   (BM=64, K=3072 -> 396 blocks)
  gemm_bf16<64, 768, 3072, 1><<<66 * 6, 256, 0, stream>>>(g, mlpw2_t, mlp_b2, out, out);
}

// Round 5
// 342.023 us; speedup vs baseline: 1.5062x; 1.0574x over previous
//
#include <hip/hip_runtime.h>
#include <hip/hip_bf16.h>

using bf16 = __hip_bfloat16;
using s8v  = __attribute__((ext_vector_type(8))) short;
using f4v  = __attribute__((ext_vector_type(4))) float;

constexpr int B_   = 4;
constexpr int P_   = 1024;
constexpr int KNB  = 32;
constexpr int D_   = 768;
constexpr int H_   = 12;
constexpr int S_   = P_ + 1;    // 1025
constexpr int M_   = B_ * S_;   // 4100
constexpr int MPAD = 4224;      // 33 * 128

#define DEVI static __device__ __forceinline__
#define WAITVM(N) asm volatile("s_waitcnt vmcnt(" #N ")" ::: "memory")
#define MEMFENCE  asm volatile("" ::: "memory")

DEVI float b2f_lo(unsigned u) { return __builtin_bit_cast(float, u << 16); }
DEVI float b2f_hi(unsigned u) { return __builtin_bit_cast(float, u & 0xffff0000u); }
DEVI float bu2f(unsigned short u) { return __builtin_bit_cast(float, (unsigned)u << 16); }
DEVI unsigned short f2bu(float f) {
  return __builtin_bit_cast(unsigned short, __float2bfloat16(f));
}

// ---------------- weight fp32 (K x N) -> bf16 transposed (N x K) ----------------
template<int KK, int NN>
__global__ __launch_bounds__(256)
void wt_conv(const float* __restrict__ W, bf16* __restrict__ Wt) {
  __shared__ float t[32][33];
  int bk = blockIdx.x * 32, bn = blockIdx.y * 32;
  int tx = threadIdx.x & 31, ty = threadIdx.x >> 5;  // ty in 0..7
#pragma unroll
  for (int i = 0; i < 32; i += 8)
    t[ty + i][tx] = W[(size_t)(bk + ty + i) * NN + bn + tx];
  __syncthreads();
#pragma unroll
  for (int i = 0; i < 32; i += 8)
    Wt[(size_t)(bn + ty + i) * KK + bk + tx] = __float2bfloat16(t[tx][ty + i]);
}

// ---------------- LayerNorm fp32 -> bf16 (row = 768) ----------------
__global__ __launch_bounds__(256)
void ln_kernel(const float* __restrict__ x, const float* __restrict__ w,
               const float* __restrict__ b, bf16* __restrict__ out) {
  int row = blockIdx.x;
  const float* xr = x + (size_t)row * D_;
  int t = threadIdx.x;
  float v0 = xr[t], v1 = xr[t + 256], v2 = xr[t + 512];
  float s = v0 + v1 + v2;
  float ss = v0 * v0 + v1 * v1 + v2 * v2;
#pragma unroll
  for (int o = 32; o; o >>= 1) { s += __shfl_xor(s, o); ss += __shfl_xor(ss, o); }
  __shared__ float sm[4], sv[4];
  if ((t & 63) == 0) { sm[t >> 6] = s; sv[t >> 6] = ss; }
  __syncthreads();
  float S = sm[0] + sm[1] + sm[2] + sm[3];
  float SS = sv[0] + sv[1] + sv[2] + sv[3];
  float mean = S * (1.f / D_);
  float var  = SS * (1.f / D_) - mean * mean;
  float inv  = rsqrtf(var + 1e-5f);
  bf16* orow = out + (size_t)row * D_;
  orow[t]       = __float2bfloat16((v0 - mean) * inv * w[t]       + b[t]);
  orow[t + 256] = __float2bfloat16((v1 - mean) * inv * w[t + 256] + b[t + 256]);
  orow[t + 512] = __float2bfloat16((v2 - mean) * inv * w[t + 512] + b[t + 512]);
}

// ---------------- bf16 GEMM, depth-3 counted-vmcnt pipeline ----------------
// C = A(rows x KSTRIDE) * Bt(NxKSTRIDE)^T over K-chunk [kbase, kbase+KCHUNK).
// grid.x = (MPAD/BM)*(N/128) swizzled blocks; grid.y = K-chunk index.
// MODE 0: + bias -> scatter to QKV buffer [3][B][S][768] bf16
// MODE 2: + bias -> gelu(exact) -> bf16 dst [M_][N]  (rows < M_ only)
// MODE 3: bf16 partial -> dst + blockIdx.y*MPAD*N (no bias)
template<int BM, int N, int KSTRIDE, int KCHUNK, int MODE>
__global__ __launch_bounds__(256)
void gemm_bf16(const bf16* __restrict__ A, const bf16* __restrict__ Bt,
               const float* __restrict__ bias, void* __restrict__ dst) {
  constexpr int MR   = BM / 32;        // m-fragments per wave (wave rows = MR*16)
  constexpr int LPS  = BM / 64 + 2;    // global_load_lds per wave per stage
  constexpr int TN   = N / 128;
  constexpr int NBLK = (MPAD / BM) * TN;
  __shared__ bf16 ldsA[3][BM * 32];
  __shared__ bf16 ldsB[3][128 * 32];

  // bijective XCD-chunked remap (m204): XCD k gets a contiguous tm-major chunk
  int bid = blockIdx.x;
  constexpr int NQ = NBLK >> 3, NR = NBLK & 7;
  int xcd = bid & 7, off = bid >> 3;
  int swz = (xcd < NR ? xcd * (NQ + 1) : NR * (NQ + 1) + (xcd - NR) * NQ) + off;
  const int tm = swz / TN, tn = swz % TN;
  const int kbase = blockIdx.y * KCHUNK;

  const int tid = threadIdx.x;
  const int wid = tid >> 6, lane = tid & 63;
  const int wr = wid >> 1, wc = wid & 1;

  auto stage = [&](int bufi, int step) {
    const int k0 = kbase + step * 32;
#pragma unroll
    for (int i = 0; i < BM / 64; ++i) {
      int c = wid * 64 + i * 256 + lane;
      int r = c >> 2, slot = c & 3;
      int gs = slot ^ ((r >> 1) & 3);  // inverse-swizzled global source (rule 21)
      const bf16* ga = A + (size_t)(tm * BM + r) * KSTRIDE + k0 + gs * 8;
      bf16* la = &ldsA[bufi][(wid * 64 + i * 256) * 8];
      __builtin_amdgcn_global_load_lds(
          (__attribute__((address_space(1))) void*)ga,
          (__attribute__((address_space(3))) void*)la, 16, 0, 0);
    }
#pragma unroll
    for (int i = 0; i < 2; ++i) {
      int c = wid * 64 + i * 256 + lane;
      int r = c >> 2, slot = c & 3;
      int gs = slot ^ ((r >> 1) & 3);
      const bf16* ga = Bt + (size_t)(tn * 128 + r) * KSTRIDE + k0 + gs * 8;
      bf16* la = &ldsB[bufi][(wid * 64 + i * 256) * 8];
      __builtin_amdgcn_global_load_lds(
          (__attribute__((address_space(1))) void*)ga,
          (__attribute__((address_space(3))) void*)la, 16, 0, 0);
    }
  };

  f4v acc[MR][4] = {};
  const int nk = KCHUNK / 32;

  stage(0, 0); stage(1, 1);   // 2 stages in flight

#pragma unroll 3
  for (int kt = 0; kt < nk; ++kt) {
    if (kt < nk - 1) {        // wait for oldest, leave 1 stage (LPS loads) in flight
      if constexpr (LPS == 4) WAITVM(4); else WAITVM(3);
    } else {
      WAITVM(0);
    }
    __builtin_amdgcn_s_barrier();   // stage(kt) visible; buf[(kt+2)%3] free (WAR ok)
    MEMFENCE;
    if (kt + 2 < nk) stage((kt + 2) % 3, kt + 2);  // 2-iteration runway

    const int cur = kt % 3;
    s8v af[MR], bfv[4];
#pragma unroll
    for (int m = 0; m < MR; ++m) {
      int row = wr * (MR * 16) + m * 16 + (lane & 15);
      int slot = (lane >> 4) ^ ((row >> 1) & 3);
      af[m] = *(const s8v*)&ldsA[cur][row * 32 + slot * 8];
    }
#pragma unroll
    for (int n = 0; n < 4; ++n) {
      int row = wc * 64 + n * 16 + (lane & 15);
      int slot = (lane >> 4) ^ ((row >> 1) & 3);
      bfv[n] = *(const s8v*)&ldsB[cur][row * 32 + slot * 8];
    }
    __builtin_amdgcn_s_setprio(1);
#pragma unroll
    for (int m = 0; m < MR; ++m)
#pragma unroll
      for (int n = 0; n < 4; ++n)
        acc[m][n] = __builtin_amdgcn_mfma_f32_16x16x32_bf16(af[m], bfv[n], acc[m][n], 0, 0, 0);
    __builtin_amdgcn_s_setprio(0);
  }

#pragma unroll
  for (int m = 0; m < MR; ++m)
#pragma unroll
    for (int n = 0; n < 4; ++n)
#pragma unroll
      for (int j = 0; j < 4; ++j) {
        int row = tm * BM + wr * (MR * 16) + m * 16 + (lane >> 4) * 4 + j;
        int col = tn * 128 + wc * 64 + n * 16 + (lane & 15);   // C: col=l&15 (m89)
        float v = acc[m][n][j];
        if (MODE == 0) {
          if (row < M_) {
            float val = v + bias[col];
            int which = col / 768, rem2 = col % 768;
            int bb = row / S_, s = row % S_;
            ((bf16*)dst)[((size_t)(which * B_ + bb) * S_ + s) * 768 + rem2] =
                __float2bfloat16(val);
          }
        } else if (MODE == 2) {
          if (row < M_) {
            float val = v + bias[col];
            val = 0.5f * val * (1.f + erff(val * 0.70710678f));
            ((bf16*)dst)[(size_t)row * N + col] = __float2bfloat16(val);
          }
        } else {
          bf16* p = (bf16*)dst + (size_t)blockIdx.y * MPAD * N;
          p[(size_t)row * N + col] = __float2bfloat16(v);
        }
      }
}

// ---------------- split-K reduce: out = (IP ? out : src) + bias + p0 + p1 ----------------
template<bool IP>
__global__ __launch_bounds__(256)
void reduceK(const bf16* __restrict__ part, const float* __restrict__ src,
             const float* __restrict__ bias, float* __restrict__ out) {
  int i = blockIdx.x * 256 + threadIdx.x;   // float4 units; M_*768/4 total
  ushort4 a = ((const ushort4*)part)[i];
  ushort4 b = ((const ushort4*)(part + (size_t)MPAD * 768))[i];
  float4 s = IP ? ((const float4*)out)[i] : ((const float4*)src)[i];
  int col = (i * 4) % D_;
  float4 bv = *(const float4*)&bias[col];
  float4 o;
  o.x = s.x + bv.x + bu2f(a.x) + bu2f(b.x);
  o.y = s.y + bv.y + bu2f(a.y) + bu2f(b.y);
  o.z = s.z + bv.z + bu2f(a.z) + bu2f(b.z);
  o.w = s.w + bv.w + bu2f(a.w) + bu2f(b.w);
  ((float4*)out)[i] = o;
}

// ---------------- cls-token attention, flash-split over 4 S-chunks ----------------
__global__ __launch_bounds__(256)
void cls_partial(const bf16* __restrict__ QKV, float* __restrict__ part) {
  int bh = blockIdx.x, c = blockIdx.y;
  int b = bh / H_, h = bh % H_;
  const bf16* q  = QKV + ((size_t)(0 * B_ + b) * S_) * D_ + h * 64;
  const bf16* Kr = QKV + ((size_t)(1 * B_ + b) * S_) * D_ + h * 64;
  const bf16* Vr = QKV + ((size_t)(2 * B_ + b) * S_) * D_ + h * 64;
  int k0 = c * 256, kn = (c == 3) ? 257 : 256;
  __shared__ float qf[64];
  __shared__ float sc[257];
  __shared__ float red[4];
  __shared__ float pv[4][64];
  int t = threadIdx.x;
  if (t < 64) qf[t] = __bfloat162float(q[t]);
  __syncthreads();
  for (int kk = t; kk < kn; kk += 256) {
    const uint4* k4 = (const uint4*)(Kr + (size_t)(k0 + kk) * D_);
    float s = 0.f;
#pragma unroll
    for (int i = 0; i < 8; ++i) {
      uint4 kv = k4[i];
      const float* q8 = &qf[i * 8];
      s += b2f_lo(kv.x) * q8[0] + b2f_hi(kv.x) * q8[1]
         + b2f_lo(kv.y) * q8[2] + b2f_hi(kv.y) * q8[3]
         + b2f_lo(kv.z) * q8[4] + b2f_hi(kv.z) * q8[5]
         + b2f_lo(kv.w) * q8[6] + b2f_hi(kv.w) * q8[7];
    }
    sc[kk] = s * 0.125f;
  }
  __syncthreads();
  float mx = -1e30f;
  for (int kk = t; kk < kn; kk += 256) mx = fmaxf(mx, sc[kk]);
#pragma unroll
  for (int o = 32; o; o >>= 1) mx = fmaxf(mx, __shfl_xor(mx, o));
  if ((t & 63) == 0) red[t >> 6] = mx;
  __syncthreads();
  float M = fmaxf(fmaxf(red[0], red[1]), fmaxf(red[2], red[3]));
  __syncthreads();
  float sum = 0.f;
  for (int kk = t; kk < kn; kk += 256) { float e = __expf(sc[kk] - M); sc[kk] = e; sum += e; }
#pragma unroll
  for (int o = 32; o; o >>= 1) sum += __shfl_xor(sum, o);
  if ((t & 63) == 0) red[t >> 6] = sum;
  __syncthreads();
  float L = red[0] + red[1] + red[2] + red[3];
  int d = t & 63, kg = t >> 6;
  float acc = 0.f;
  for (int kk = kg; kk < kn; kk += 4)
    acc += sc[kk] * __bfloat162float(Vr[(size_t)(k0 + kk) * D_ + d]);
  pv[kg][d] = acc;
  __syncthreads();
  float* pp = part + ((size_t)bh * 4 + c) * 68;
  if (t < 64) pp[4 + t] = pv[0][t] + pv[1][t] + pv[2][t] + pv[3][t];
  else if (t == 64) pp[0] = M;
  else if (t == 65) pp[1] = L;
}

__global__ __launch_bounds__(64)
void cls_combine(const float* __restrict__ part, bf16* __restrict__ out) {
  int bh = blockIdx.x, t = threadIdx.x;
  const float* pp = part + (size_t)bh * 4 * 68;
  float m0 = pp[0], m1 = pp[68], m2 = pp[136], m3 = pp[204];
  float M = fmaxf(fmaxf(m0, m1), fmaxf(m2, m3));
  float e0 = __expf(m0 - M), e1 = __expf(m1 - M), e2 = __expf(m2 - M), e3 = __expf(m3 - M);
  float L = pp[1] * e0 + pp[69] * e1 + pp[137] * e2 + pp[205] * e3;
  float o = pp[4 + t] * e0 + pp[72 + t] * e1 + pp[140 + t] * e2 + pp[208 + t] * e3;
  int b = bh / H_, h = bh % H_;
  out[(size_t)(b * S_) * D_ + h * 64 + t] = __float2bfloat16(o / L);
}

// ---------------- routed attention: one wave per (b,p,h), no barriers ----------------
__global__ __launch_bounds__(256)
void routed_attn(const bf16* __restrict__ QKV, const int* __restrict__ routes,
                 bf16* __restrict__ out) {
  int unit = blockIdx.x * 4 + (threadIdx.x >> 6);  // (b*P + p)*H + h ; b slowest
  int lane = threadIdx.x & 63;
  int h = unit % H_;
  int bp = unit / H_;
  int p = bp % P_, b = bp / P_;

  int k = lane & 31, hi = lane >> 5;
  int r = routes[p * KNB + k] + 1;                 // gathered token row

  const bf16* Qp = QKV + ((size_t)(0 * B_ + b) * S_ + (p + 1)) * D_ + h * 64 + hi * 32;
  const bf16* Kb = QKV + ((size_t)(1 * B_ + b) * S_) * D_;
  const bf16* Vb = QKV + ((size_t)(2 * B_ + b) * S_) * D_;

  // phase 1: 32-dim half-dot per lane
  const uint4* q4 = (const uint4*)Qp;
  const uint4* k4 = (const uint4*)(Kb + (size_t)r * D_ + h * 64 + hi * 32);
  float dot = 0.f;
#pragma unroll
  for (int i = 0; i < 4; ++i) {
    uint4 qv = q4[i], kv = k4[i];
    dot += b2f_lo(kv.x) * b2f_lo(qv.x) + b2f_hi(kv.x) * b2f_hi(qv.x)
         + b2f_lo(kv.y) * b2f_lo(qv.y) + b2f_hi(kv.y) * b2f_hi(qv.y)
         + b2f_lo(kv.z) * b2f_lo(qv.z) + b2f_hi(kv.z) * b2f_hi(qv.z)
         + b2f_lo(kv.w) * b2f_lo(qv.w) + b2f_hi(kv.w) * b2f_hi(qv.w);
  }
  dot += __shfl_xor(dot, 32);
  float sc = dot * 0.125f;

  // softmax over the 32 keys (both halves hold identical values)
  float mx = sc;
#pragma unroll
  for (int o = 16; o; o >>= 1) mx = fmaxf(mx, __shfl_xor(mx, o));
  float w = __expf(sc - mx);
  float sum = w;
#pragma unroll
  for (int o = 16; o; o >>= 1) sum += __shfl_xor(sum, o);
  float inv = 1.f / sum;

  // phase 2: lane = (key-octet, dim-chunk); uint4 V loads
  int c = lane & 7, kr0 = lane >> 3;
  float acc[8] = {};
#pragma unroll
  for (int j = 0; j < 4; ++j) {
    int kj = (kr0 & 7) + 8 * j;          // 0..31
    float wj = __shfl(w, kj);
    int rj = __shfl(r, kj);
    uint4 vv = *(const uint4*)(Vb + (size_t)rj * D_ + h * 64 + c * 8);
    acc[0] += wj * b2f_lo(vv.x); acc[1] += wj * b2f_hi(vv.x);
    acc[2] += wj * b2f_lo(vv.y); acc[3] += wj * b2f_hi(vv.y);
    acc[4] += wj * b2f_lo(vv.z); acc[5] += wj * b2f_hi(vv.z);
    acc[6] += wj * b2f_lo(vv.w); acc[7] += wj * b2f_hi(vv.w);
  }
#pragma unroll
  for (int s = 8; s < 64; s <<= 1)
#pragma unroll
    for (int d = 0; d < 8; ++d) acc[d] += __shfl_xor(acc[d], s);

  if (lane < 8) {
    s8v o;
#pragma unroll
    for (int d = 0; d < 8; ++d) o[d] = (short)f2bu(acc[d] * inv);
    *(s8v*)(out + ((size_t)(b * S_ + p + 1)) * D_ + h * 64 + c * 8) = o;
  }
}

extern "C" void kernel_launch(void* const* d_in, const int* in_sizes, int n_in,
                              void* d_out, int out_size, void* d_ws, size_t ws_size,
                              hipStream_t stream) {
  const float* x      = (const float*)d_in[0];
  const int*   routes = (const int*)d_in[1];
  const float* qkv_w  = (const float*)d_in[2];
  const float* qkv_b  = (const float*)d_in[3];
  const float* proj_w = (const float*)d_in[4];
  const float* proj_b = (const float*)d_in[5];
  const float* ln1_w  = (const float*)d_in[6];
  const float* ln1_b  = (const float*)d_in[7];
  const float* ln2_w  = (const float*)d_in[8];
  const float* ln2_b  = (const float*)d_in[9];
  const float* mlp_w1 = (const float*)d_in[10];
  const float* mlp_b1 = (const float*)d_in[11];
  const float* mlp_w2 = (const float*)d_in[12];
  const float* mlp_b2 = (const float*)d_in[13];
  float* out = (float*)d_out;

  // workspace layout (~52.5 MB, same footprint as proven rounds)
  bf16* qkvw_t  = (bf16*)d_ws;                       // [2304][768]
  bf16* projw_t = qkvw_t + 2304 * 768;               // [768][768]
  bf16* mlpw1_t = projw_t + 768 * 768;               // [3072][768]
  bf16* mlpw2_t = mlpw1_t + 3072 * 768;              // [768][3072]
  bf16* xnA     = mlpw2_t + 768 * 3072;              // [4224][768]
  bf16* qkvbuf  = xnA + (size_t)MPAD * 768;          // [3][B][S][768] s-major
  bf16* attn    = qkvbuf + (size_t)3 * B_ * S_ * 768;  // [4224][768]
  bf16* h2      = attn + (size_t)MPAD * 768;         // [4224][768]
  // aliases (lifetime-checked):
  bf16* g       = xnA;   // [M_][3072] = 25.2MB over xnA+qkvbuf (both dead by mlp1)
  bf16* projp   = xnA;   // proj partials [2][MPAD][768] = 13MB (xnA + qkvbuf head, dead)
  bf16* mlp2p   = attn;  // mlp2 partials [2][MPAD][768] = 13MB over attn+h2 (dead by mlp2)
  float* clsp   = (float*)(attn + (size_t)M_ * 768); // cls partials in attn row padding

  wt_conv<768, 2304><<<dim3(24, 72), 256, 0, stream>>>(qkv_w, qkvw_t);
  wt_conv<768, 768><<<dim3(24, 24), 256, 0, stream>>>(proj_w, projw_t);
  wt_conv<768, 3072><<<dim3(24, 96), 256, 0, stream>>>(mlp_w1, mlpw1_t);
  wt_conv<3072, 768><<<dim3(96, 24), 256, 0, stream>>>(mlp_w2, mlpw2_t);

  ln_kernel<<<M_, 256, 0, stream>>>(x, ln1_w, ln1_b, xnA);

  gemm_bf16<128, 2304, 768, 768, 0><<<33 * 18, 256, 0, stream>>>(xnA, qkvw_t, qkv_b, qkvbuf);

  routed_attn<<<(B_ * P_ * H_) / 4, 256, 0, stream>>>(qkvbuf, routes, attn);
  cls_partial<<<dim3(B_ * H_, 4), 256, 0, stream>>>(qkvbuf, clsp);
  cls_combine<<<B_ * H_, 64, 0, stream>>>(clsp, attn);

  // proj split-K x2: partials then out = x + proj_b + p0 + p1
  gemm_bf16<64, 768, 768, 384, 3><<<dim3(66 * 6, 2), 256, 0, stream>>>(attn, projw_t, nullptr, projp);
  reduceK<false><<<(M_ * D_) / 1024, 256, 0, stream>>>(projp, x, proj_b, out);

  ln_kernel<<<M_, 256, 0, stream>>>(out, ln2_w, ln2_b, h2);

  gemm_bf16<128, 3072, 768, 768, 2><<<33 * 24, 256, 0, stream>>>(h2, mlpw1_t, mlp_b1, g);

  // mlp2 split-K x2: partials then out += mlp_b2 + p0 + p1
  gemm_bf16<64, 768, 3072, 1536, 3><<<dim3(66 * 6, 2), 256, 0, stream>>>(g, mlpw2_t, nullptr, mlp2p);
  reduceK<true><<<(M_ * D_) / 1024, 256, 0, stream>>>(mlp2p, nullptr, mlp_b2, out);
}